// Round 1
// baseline (137.938 us; speedup 1.0000x reference)
//
#include <hip/hip_runtime.h>

#define BB 64
#define TT 4096
#define CC 51
#define DD 64
#define LN_EPS 1e-5f

typedef __attribute__((ext_vector_type(8))) short short8;
typedef __attribute__((ext_vector_type(4))) float f32x4;
typedef __attribute__((ext_vector_type(4))) int i32x4;

union FragU { int i[4]; i32x4 v; short8 s; };

// DPP control codes (verified R3-R5)
#define DPP_QP_1032   0xB1
#define DPP_QP_2301   0x4E
#define DPP_ROW_HMIRR 0x141
#define DPP_ROW_MIRR  0x140

__device__ __forceinline__ float dpp_add(float v, int tag) {
  int t;
  switch (tag) {
    case 0: t = __builtin_amdgcn_update_dpp(0, __float_as_int(v), DPP_QP_1032,   0xF, 0xF, true); break;
    case 1: t = __builtin_amdgcn_update_dpp(0, __float_as_int(v), DPP_QP_2301,   0xF, 0xF, true); break;
    case 2: t = __builtin_amdgcn_update_dpp(0, __float_as_int(v), DPP_ROW_HMIRR, 0xF, 0xF, true); break;
    default: t = __builtin_amdgcn_update_dpp(0, __float_as_int(v), DPP_ROW_MIRR, 0xF, 0xF, true); break;
  }
  return v + __int_as_float(t);
}
__device__ __forceinline__ float allsum16(float v) {
  v = dpp_add(v, 0); v = dpp_add(v, 1); v = dpp_add(v, 2); v = dpp_add(v, 3);
  return v;
}
__device__ __forceinline__ float allsum64(float v) {
  v = allsum16(v);
  v += __shfl_xor(v, 16, 64);
  v += __shfl_xor(v, 32, 64);
  return v;
}

// fp32 -> packed (bf16 hi | bf16 lo) dword; k=2c gets hi (low short), 2c+1 lo
__device__ __forceinline__ int pack_hl(float x) {
  const unsigned u = __float_as_uint(x);
  const unsigned h = u >> 16;
  const float hf = __uint_as_float(u & 0xFFFF0000u);
  const unsigned l = __float_as_uint(x - hf) >> 16;
  return (int)(h | (l << 16));
}

// ws layout:
//   floats [0 .. 8191]        : per-b {bias[64], lnconst[64]}  (b*128 + ...)
//   ints   [8192f ..]         : tabMU[4096], tabCU[4096]  packed W B-frags,
//                               indexed tab[ks][n][q][j] = ks*1024 + n*16 + q*4 + j
// grid 65: blocks 0..63 do per-b bias/lnconst; block 64 packs W.
__global__ void ipmask_setup4(const float* __restrict__ W,
                              const float* __restrict__ Wm,
                              const float* __restrict__ gamma,
                              const float* __restrict__ beta,
                              const int* __restrict__ smask,
                              float* __restrict__ ws) {
  const int t = threadIdx.x;
  if (blockIdx.x >= BB) {
    // ---- pack grid-invariant W fragments (sensor mask now lives on A side) ----
    int* tabMU = (int*)(ws + 2 * BB * DD);
    int* tabCU = tabMU + 4096;
#pragma unroll
    for (int e = 0; e < 16; ++e) {
      const int idx = t * 16 + e;
      const int j = idx & 3, qq = (idx >> 2) & 3, n = (idx >> 4) & 63, ks = idx >> 10;
      const int c = ks * 16 + qq * 4 + j;
      const float w = (c < CC) ? W[c * DD + n] : 0.0f;
      const unsigned u = __float_as_uint(w);
      const unsigned h = u >> 16;
      const float hf = __uint_as_float(u & 0xFFFF0000u);
      const unsigned l = __float_as_uint(w - hf) >> 16;
      tabMU[idx] = (int)(h | (h << 16));
      tabCU[idx] = (int)l;
    }
    return;
  }
  __shared__ float red[8][64];
  const int L = t & 63, w = t >> 6;
  const int b = blockIdx.x;
  const int c0 = w * 13, c1 = (c0 + 13 < CC) ? c0 + 13 : CC;
  float bs = 0.0f, f = 0.0f;
  for (int c = c0; c < c1; ++c) {
    const float wmv = Wm[c * DD + L];
    const float sf = (float)smask[b * CC + c];
    bs = fmaf(sf, wmv, bs);
    f += wmv;
  }
  red[w * 2][L] = bs;
  red[w * 2 + 1][L] = f;
  __syncthreads();
  if (w == 0) {
    bs = (red[0][L] + red[2][L]) + (red[4][L] + red[6][L]);
    f  = (red[1][L] + red[3][L]) + (red[5][L] + red[7][L]);
    ws[b * 128 + L] = bs;
    const float s1 = allsum64(f);
    const float s2 = allsum64(f * f);
    const float mu = s1 * (1.0f / 64.0f);
    const float vr = fmaf(-mu, mu, s2 * (1.0f / 64.0f));
    const float rs = rsqrtf(vr + LN_EPS);
    ws[b * 128 + 64 + L] = fmaf((f - mu) * rs, gamma[L], beta[L]);
  }
}

// ---- main: LDS-free MFMA, tm-skipped x loads, table-loaded B frags, NT stores ----
__global__ __launch_bounds__(256, 2)
void ipmask_mfma4(const float* __restrict__ x,
                  const float* __restrict__ gamma, const float* __restrict__ beta,
                  const int* __restrict__ tmask, const int* __restrict__ smask,
                  const float* __restrict__ ws, float* __restrict__ out) {
  const int t = threadIdx.x, L = t & 63;
  const int q = L >> 4, m16 = L & 15;
  const int gw = (blockIdx.x << 2) + (t >> 6);      // 4096 waves
  const int b = gw >> 6;
  const int rowBase = (b << 12) + ((gw & 63) << 6); // 64 rows per wave

  const int* smB = smask + b * CC;
  const int* tabMU = (const int*)(ws + 2 * BB * DD);
  const int* tabCU = tabMU + 4096;

  const int tmv = tmask[rowBase + L];               // coalesced, 1 dword/lane

  // sensor-mask factor per (ks,j): (1 - sm[c]) as float (c >= CC -> 0)
  float msk[4][4];
#pragma unroll
  for (int ks = 0; ks < 4; ++ks)
#pragma unroll
    for (int j = 0; j < 4; ++j) {
      const int c = ks * 16 + q * 4 + j;
      const int sv = (c < CC) ? smB[c] : 1;
      msk[ks][j] = sv ? 0.0f : 1.0f;
    }

  // ---- x loads upfront, skipping fully time-masked rows (their output is lnconst) ----
  float xf[4][4][4];   // [mt][ks][j]
#pragma unroll
  for (int mt = 0; mt < 4; ++mt) {
    const int tm_r = __shfl(tmv, mt * 16 + m16, 64);
    const float* xr = x + (size_t)(rowBase + mt * 16 + m16) * CC;
    if (!tm_r) {
#pragma unroll
      for (int ks = 0; ks < 4; ++ks)
#pragma unroll
        for (int j = 0; j < 4; ++j) {
          const int c = ks * 16 + q * 4 + j;
          xf[mt][ks][j] = (c < CC) ? xr[c] * msk[ks][j] : 0.0f;
        }
    } else {
#pragma unroll
      for (int ks = 0; ks < 4; ++ks)
#pragma unroll
        for (int j = 0; j < 4; ++j) xf[mt][ks][j] = 0.0f;
    }
  }

  // ---- acc init = bias ----
  f32x4 acc[4][4];
#pragma unroll
  for (int nt = 0; nt < 4; ++nt) {
    const float bias_nt = ws[b * 128 + nt * 16 + m16];
#pragma unroll
    for (int mt = 0; mt < 4; ++mt) {
      acc[mt][nt][0] = bias_nt; acc[mt][nt][1] = bias_nt;
      acc[mt][nt][2] = bias_nt; acc[mt][nt][3] = bias_nt;
    }
  }

#pragma unroll
  for (int ks = 0; ks < 4; ++ks) {
    // B frags: straight dwordx4 loads from the precomputed table (L1/L2-hot, 32 KB)
    FragU bmu[4], bcu[4];
#pragma unroll
    for (int nt = 0; nt < 4; ++nt) {
      const int base = ks * 1024 + (nt * 16 + m16) * 16 + q * 4;
      bmu[nt].v = *(const i32x4*)&tabMU[base];
      bcu[nt].v = *(const i32x4*)&tabCU[base];
    }
#pragma unroll
    for (int mt = 0; mt < 4; ++mt) {
      FragU au;
#pragma unroll
      for (int j = 0; j < 4; ++j) au.i[j] = pack_hl(xf[mt][ks][j]);
#pragma unroll
      for (int nt = 0; nt < 4; ++nt) {
        acc[mt][nt] = __builtin_amdgcn_mfma_f32_16x16x32_bf16(au.s, bmu[nt].s, acc[mt][nt], 0, 0, 0);
        acc[mt][nt] = __builtin_amdgcn_mfma_f32_16x16x32_bf16(au.s, bcu[nt].s, acc[mt][nt], 0, 0, 0);
      }
    }
  }

  // ---- epilogue: LN per row, tmask via shfl, NT stores ----
  float g_[4], b_[4], cons_[4];
#pragma unroll
  for (int nt = 0; nt < 4; ++nt) {
    g_[nt] = gamma[nt * 16 + m16];
    b_[nt] = beta[nt * 16 + m16];
    cons_[nt] = ws[b * 128 + 64 + nt * 16 + m16];
  }
#pragma unroll
  for (int mt = 0; mt < 4; ++mt) {
#pragma unroll
    for (int rg = 0; rg < 4; ++rg) {
      float su = 0.0f, sq = 0.0f;
#pragma unroll
      for (int nt = 0; nt < 4; ++nt) {
        const float v = acc[mt][nt][rg];
        su += v;
        sq = fmaf(v, v, sq);
      }
      su = allsum16(su);
      sq = allsum16(sq);
      const float mu = su * (1.0f / 64.0f);
      const float vr = fmaf(-mu, mu, sq * (1.0f / 64.0f));
      const float rs = rsqrtf(vr + LN_EPS);
      const int rloc = mt * 16 + q * 4 + rg;
      const int tm = __shfl(tmv, rloc, 64);
      const size_t obase = (size_t)(rowBase + rloc) * DD;
#pragma unroll
      for (int nt = 0; nt < 4; ++nt) {
        float val = fmaf((acc[mt][nt][rg] - mu) * rs, g_[nt], b_[nt]);
        if (tm) val = cons_[nt];
        __builtin_nontemporal_store(val, &out[obase + nt * 16 + m16]);
      }
    }
  }
}

extern "C" void kernel_launch(void* const* d_in, const int* in_sizes, int n_in,
                              void* d_out, int out_size, void* d_ws, size_t ws_size,
                              hipStream_t stream) {
  const float* x     = (const float*)d_in[0];
  const float* W     = (const float*)d_in[1];
  const float* Wm    = (const float*)d_in[2];
  const float* gamma = (const float*)d_in[3];
  const float* beta  = (const float*)d_in[4];
  const int*   tmask = (const int*)d_in[5];
  const int*   smask = (const int*)d_in[6];
  float* out = (float*)d_out;
  float* ws  = (float*)d_ws;

  ipmask_setup4<<<dim3(BB + 1), dim3(256), 0, stream>>>(W, Wm, gamma, beta, smask, ws);
  ipmask_mfma4<<<dim3(1024), dim3(256), 0, stream>>>(
      x, gamma, beta, tmask, smask, ws, out);
}

// Round 2
// 126.573 us; speedup vs baseline: 1.0898x; 1.0898x over previous
//
#include <hip/hip_runtime.h>

#define BB 64
#define TT 4096
#define CC 51
#define DD 64
#define LN_EPS 1e-5f

typedef __attribute__((ext_vector_type(8))) short short8;
typedef __attribute__((ext_vector_type(4))) float f32x4;

union FragU { int i[4]; short8 s; };

// DPP control codes (verified R3-R5)
#define DPP_QP_1032   0xB1
#define DPP_QP_2301   0x4E
#define DPP_ROW_HMIRR 0x141
#define DPP_ROW_MIRR  0x140

__device__ __forceinline__ float dpp_add(float v, int tag) {
  int t;
  switch (tag) {
    case 0: t = __builtin_amdgcn_update_dpp(0, __float_as_int(v), DPP_QP_1032,   0xF, 0xF, true); break;
    case 1: t = __builtin_amdgcn_update_dpp(0, __float_as_int(v), DPP_QP_2301,   0xF, 0xF, true); break;
    case 2: t = __builtin_amdgcn_update_dpp(0, __float_as_int(v), DPP_ROW_HMIRR, 0xF, 0xF, true); break;
    default: t = __builtin_amdgcn_update_dpp(0, __float_as_int(v), DPP_ROW_MIRR, 0xF, 0xF, true); break;
  }
  return v + __int_as_float(t);
}
__device__ __forceinline__ float allsum16(float v) {
  v = dpp_add(v, 0); v = dpp_add(v, 1); v = dpp_add(v, 2); v = dpp_add(v, 3);
  return v;
}
__device__ __forceinline__ float allsum64(float v) {
  v = allsum16(v);
  v += __shfl_xor(v, 16, 64);
  v += __shfl_xor(v, 32, 64);
  return v;
}

// fp32 -> packed (bf16 hi | bf16 lo) dword; k=2c gets hi (low short), 2c+1 lo
__device__ __forceinline__ int pack_hl(float x) {
  const unsigned u = __float_as_uint(x);
  const unsigned h = u >> 16;
  const float hf = __uint_as_float(u & 0xFFFF0000u);
  const unsigned l = __float_as_uint(x - hf) >> 16;
  return (int)(h | (l << 16));
}

// ---- single fused kernel: per-block bias/lnconst + LDS-free MFMA + LN epilogue ----
// All 4 waves of a block share the same b (16 blocks per b), so each block
// redundantly computes its b's bias[64]/lnconst[64] from Wm/smask (13KB, L2-hot),
// overlapped with the upfront x-load burst. No setup kernel, no ws.
__global__ __launch_bounds__(256, 2)
void ipmask_mfma5(const float* __restrict__ x, const float* __restrict__ W,
                  const float* __restrict__ Wm,
                  const float* __restrict__ gamma, const float* __restrict__ beta,
                  const int* __restrict__ tmask, const int* __restrict__ smask,
                  float* __restrict__ out) {
  const int t = threadIdx.x, L = t & 63, w = t >> 6;
  const int q = L >> 4, m16 = L & 15;
  const int gw = (blockIdx.x << 2) + w;             // 4096 waves
  const int b = gw >> 6;
  const int rowBase = (b << 12) + ((gw & 63) << 6); // 64 rows per wave

  const int* smB = smask + b * CC;

  // ---- all x loads upfront, row-burst order: lines fetched exactly once ----
  float xf[4][4][4];   // [mt][ks][j]
#pragma unroll
  for (int mt = 0; mt < 4; ++mt) {
    const float* xr = x + (size_t)(rowBase + mt * 16 + m16) * CC;
#pragma unroll
    for (int ks = 0; ks < 4; ++ks) {
#pragma unroll
      for (int j = 0; j < 4; ++j) {
        const int c = ks * 16 + q * 4 + j;
        xf[mt][ks][j] = (c < CC) ? xr[c] : 0.0f;
      }
    }
  }
  const int tmv = tmask[rowBase + L];                // coalesced, 1 dword/lane

  // ---- fused per-b bias + lnconst (overlaps x-load latency) ----
  __shared__ float red[8][64];
  {
    const int c0 = w * 13, c1 = (c0 + 13 < CC) ? c0 + 13 : CC;
    float bs = 0.0f, f = 0.0f;
    for (int c = c0; c < c1; ++c) {
      const float wmv = Wm[c * DD + L];
      const float sf = (float)smB[c];
      bs = fmaf(sf, wmv, bs);
      f += wmv;
    }
    red[w * 2][L] = bs;
    red[w * 2 + 1][L] = f;
  }
  __syncthreads();
  const float gl = gamma[L], bl = beta[L];
  float biasL, consL;
  {
    const float bs = (red[0][L] + red[2][L]) + (red[4][L] + red[6][L]);
    const float f  = (red[1][L] + red[3][L]) + (red[5][L] + red[7][L]);
    biasL = bs;
    const float s1 = allsum64(f);
    const float s2 = allsum64(f * f);
    const float mu = s1 * (1.0f / 64.0f);
    const float vr = fmaf(-mu, mu, s2 * (1.0f / 64.0f));
    const float rs = rsqrtf(vr + LN_EPS);
    consL = fmaf((f - mu) * rs, gl, bl);
  }
  // redistribute per-n values to the (nt,m16) fragment layout via shfl
  float bias_[4], cons_[4], g_[4], b_[4];
#pragma unroll
  for (int nt = 0; nt < 4; ++nt) {
    const int src = nt * 16 + m16;
    bias_[nt] = __shfl(biasL, src, 64);
    cons_[nt] = __shfl(consL, src, 64);
    g_[nt]    = __shfl(gl, src, 64);
    b_[nt]    = __shfl(bl, src, 64);
  }

  // ---- acc init = bias ----
  f32x4 acc[4][4];
#pragma unroll
  for (int nt = 0; nt < 4; ++nt) {
#pragma unroll
    for (int mt = 0; mt < 4; ++mt) {
      acc[mt][nt][0] = bias_[nt]; acc[mt][nt][1] = bias_[nt];
      acc[mt][nt][2] = bias_[nt]; acc[mt][nt][3] = bias_[nt];
    }
  }

#pragma unroll
  for (int ks = 0; ks < 4; ++ks) {
    // B frags rebuilt per ks (W is L1-hot: 13 KB)
    FragU bmu[4], bcu[4];
#pragma unroll
    for (int j = 0; j < 4; ++j) {
      const int c = ks * 16 + q * 4 + j;
      const int smv = (c < CC) ? smB[c] : 1;
#pragma unroll
      for (int nt = 0; nt < 4; ++nt) {
        const int n = nt * 16 + m16;
        float we = 0.0f;
        if (c < CC) we = W[c * DD + n];
        if (smv) we = 0.0f;
        const unsigned u = __float_as_uint(we);
        const unsigned h = u >> 16;
        const float hf = __uint_as_float(u & 0xFFFF0000u);
        const unsigned l = __float_as_uint(we - hf) >> 16;
        bmu[nt].i[j] = (int)(h | (h << 16));
        bcu[nt].i[j] = (int)l;
      }
    }
#pragma unroll
    for (int mt = 0; mt < 4; ++mt) {
      FragU au;
#pragma unroll
      for (int j = 0; j < 4; ++j) au.i[j] = pack_hl(xf[mt][ks][j]);
#pragma unroll
      for (int nt = 0; nt < 4; ++nt) {
        acc[mt][nt] = __builtin_amdgcn_mfma_f32_16x16x32_bf16(au.s, bmu[nt].s, acc[mt][nt], 0, 0, 0);
        acc[mt][nt] = __builtin_amdgcn_mfma_f32_16x16x32_bf16(au.s, bcu[nt].s, acc[mt][nt], 0, 0, 0);
      }
    }
  }

  // ---- epilogue: LN per row, tmask via shfl, NT stores ----
#pragma unroll
  for (int mt = 0; mt < 4; ++mt) {
#pragma unroll
    for (int rg = 0; rg < 4; ++rg) {
      float su = 0.0f, sq = 0.0f;
#pragma unroll
      for (int nt = 0; nt < 4; ++nt) {
        const float v = acc[mt][nt][rg];
        su += v;
        sq = fmaf(v, v, sq);
      }
      su = allsum16(su);
      sq = allsum16(sq);
      const float mu = su * (1.0f / 64.0f);
      const float vr = fmaf(-mu, mu, sq * (1.0f / 64.0f));
      const float rs = rsqrtf(vr + LN_EPS);
      const int rloc = mt * 16 + q * 4 + rg;
      const int tm = __shfl(tmv, rloc, 64);
      const size_t obase = (size_t)(rowBase + rloc) * DD;
#pragma unroll
      for (int nt = 0; nt < 4; ++nt) {
        float val = fmaf((acc[mt][nt][rg] - mu) * rs, g_[nt], b_[nt]);
        if (tm) val = cons_[nt];
        __builtin_nontemporal_store(val, &out[obase + nt * 16 + m16]);
      }
    }
  }
}

extern "C" void kernel_launch(void* const* d_in, const int* in_sizes, int n_in,
                              void* d_out, int out_size, void* d_ws, size_t ws_size,
                              hipStream_t stream) {
  const float* x     = (const float*)d_in[0];
  const float* W     = (const float*)d_in[1];
  const float* Wm    = (const float*)d_in[2];
  const float* gamma = (const float*)d_in[3];
  const float* beta  = (const float*)d_in[4];
  const int*   tmask = (const int*)d_in[5];
  const int*   smask = (const int*)d_in[6];
  float* out = (float*)d_out;

  ipmask_mfma5<<<dim3(1024), dim3(256), 0, stream>>>(
      x, W, Wm, gamma, beta, tmask, smask, out);
}